// Round 14
// baseline (2705.058 us; speedup 1.0000x reference)
//
#include <hip/hip_runtime.h>

// Multi-layer tanh RNN — R14: wave-private pipeline, ZERO barriers.
// Insight: a wave that owns ALL 100 output columns for its 16 batch rows has
// a wave-private recurrence (h_{t+1}[rows] <- h_t[same rows]). Single-wave
// blocks (64 thr) need no __syncthreads ever: C->A layout transform goes
// through LDS with per-wave in-order DS + compiler lgkmcnt only, and the
// batch-last RELEASE covers all of the block's stores (no cross-wave race).
// Block = (layer, chunk-of-16-rows): grid 10x32 = 320 x 64 threads.
// Weights: single-plane RTN bf16, reg-resident: Bf[8 kc][7 ntl] = 224 VGPR
// (2-plane doesn't fit; ~2^-9 weight noise, margin to 9.8e-3 threshold).
// Activations: single-plane RTN bf16 (R13-proven). MFMA 16x16x32, 7 indep
// acc chains. Ring/flag protocol = R8 exact (agent scope, K=16/RD=32).
// R12 lesson respected: M=16 tile fully used (BC=16 rows/wave).

#define HH   100   // hidden
#define HS   132   // padded LDS row stride (floats)
#define NL   10    // layers
#define BBS  512   // batch
#define TTS  512   // time
#define NB   32    // batch chunks
#define BC   16    // batch rows per wave
#define NT   64    // threads per block == one wave
#define NTL  7     // column tiles (7*16 = 112 >= 100)

typedef __attribute__((ext_vector_type(8))) short short8;
typedef __attribute__((ext_vector_type(4))) float f32x4;
typedef __attribute__((ext_vector_type(4))) unsigned int u32x4;

__global__ void init_ws_kernel(int* wsi) {
  int i = blockIdx.x * blockDim.x + threadIdx.x;
  if (i < 16384) wsi[i] = 0;   // zero both flag regions (64KB)
}

__device__ __forceinline__ int flag_idx(int iface, int chunk) {
  return (iface * NB + chunk) * 16;
}

__device__ __forceinline__ float fast_tanh(float v) {
  float e = __expf(2.0f * v);
  return 1.0f - 2.0f * __builtin_amdgcn_rcpf(e + 1.0f);
}

// Round-to-nearest bf16 pack of a fp32 pair
__device__ __forceinline__ unsigned pack_rtn(float x0, float x1) {
  unsigned u0 = __float_as_uint(x0) + 0x8000u;
  unsigned u1 = __float_as_uint(x1) + 0x8000u;
  return (u0 >> 16) | (u1 & 0xFFFF0000u);
}

__device__ __forceinline__ short8 build1(f32x4 lo, f32x4 hi) {
  u32x4 w;
  w[0] = pack_rtn(lo[0], lo[1]);
  w[1] = pack_rtn(lo[2], lo[3]);
  w[2] = pack_rtn(hi[0], hi[1]);
  w[3] = pack_rtn(hi[2], hi[3]);
  return __builtin_bit_cast(short8, w);
}

__global__ __launch_bounds__(NT, 1) void rnn_pipe(
    const float* __restrict__ x,     // [B,T,1]
    const float* __restrict__ h0,    // [L,B,H]
    const float* __restrict__ Wih0,  // [H,1]
    const float* __restrict__ Wih,   // [L-1,H,H]
    const float* __restrict__ Whh,   // [L,H,H]
    const float* __restrict__ bih,   // [L,H]
    const float* __restrict__ bhh,   // [L,H]
    const float* __restrict__ Wout,  // [1,H]
    const float* __restrict__ bout,  // [1]
    float* __restrict__ out,         // [B*T] outs ++ [L*B*H] h_final
    float* __restrict__ ring,
    int*   __restrict__ wsi,
    int Kv, int RDv)
{
  const int layer = blockIdx.x / NB;
  const int chunk = blockIdx.x % NB;
  const int tid   = threadIdx.x;      // 0..63, one wave
  const int Km = Kv - 1, RDm = RDv - 1;

  const int quad = tid >> 4, lp = tid & 15;

  // Recurrent state, double-buffered; cols >= HH stay 0 forever.
  __shared__ float hb[2][BC][HS];     // 2*16*132*4 = 16.9 KB

  for (int i = tid; i < 2 * BC * HS; i += NT) (&hb[0][0][0])[i] = 0.f;
  for (int idx = tid; idx < BC * HH; idx += NT)
    hb[0][idx / HH][idx % HH] =
        h0[((size_t)layer * BBS + chunk * BC + idx / HH) * HH + idx % HH];

  // ---- per-lane constants (col = ntl*16 + lp) ----
  float br[NTL], w0r[NTL], wo[NTL];
  #pragma unroll
  for (int ntl = 0; ntl < NTL; ++ntl) {
    const int col = ntl * 16 + lp;
    br[ntl]  = (col < HH) ? (bih[layer * HH + col] + bhh[layer * HH + col]) : 0.f;
    w0r[ntl] = (col < HH) ? Wih0[col] : 0.f;
    wo[ntl]  = (col < HH) ? Wout[col] : 0.f;
  }
  const float boutv = bout[0];

  // ---- reg-resident single-plane weights: fused [Whh k0..99 ; Wih k128..227]
  // B[n = ntl*16+lp][k = kc*32 + quad*8 + j]
  short8 Bf[8][NTL];   // 224 VGPRs
  #pragma unroll
  for (int kc = 0; kc < 8; ++kc) {
    #pragma unroll
    for (int ntl = 0; ntl < NTL; ++ntl) {
      const int n = ntl * 16 + lp;
      f32x4 wlo = {}, whi = {};
      #pragma unroll
      for (int j = 0; j < 8; ++j) {
        const int k = kc * 32 + quad * 8 + j;
        float w = 0.f;
        if (kc < 4) {
          if (k < HH && n < HH) w = Whh[(size_t)layer * HH * HH + n * HH + k];
        } else {
          const int kk = k - 128;
          if (layer > 0 && kk >= 0 && kk < HH && n < HH)
            w = Wih[(size_t)(layer - 1) * HH * HH + n * HH + kk];
        }
        if (j < 4) wlo[j] = w; else whi[j - 4] = w;
      }
      Bf[kc][ntl] = build1(wlo, whi);
    }
  }

  // ---- flags / ring (R8-proven protocol, agent scope) ----
  int* prog_in  = (layer > 0)      ? wsi + flag_idx(layer - 1, chunk)        : nullptr;
  int* cons_in  = (layer > 0)      ? wsi + 8192 + flag_idx(layer - 1, chunk) : nullptr;
  int* prog_out = (layer < NL - 1) ? wsi + flag_idx(layer, chunk)            : nullptr;
  int* cons_out = (layer < NL - 1) ? wsi + 8192 + flag_idx(layer, chunk)     : nullptr;
  const size_t slot_sz = (size_t)BC * HH;  // 1600 floats
  const float* ring_in = (layer > 0)
      ? ring + (size_t)((layer - 1) * NB + chunk) * RDv * slot_sz : nullptr;
  float* ring_out = (layer < NL - 1)
      ? ring + (size_t)(layer * NB + chunk) * RDv * slot_sz : nullptr;

  // consumer A-fragments (inp rows), fp32, reg-carried with 1-step prefetch
  f32x4 a_cur[4][2], a_nxt[4][2];
  bool have_next = false;
  float xr[4] = {}, px[4] = {};
  if (layer == 0) {
    #pragma unroll
    for (int r = 0; r < 4; ++r)
      xr[r] = x[(size_t)(chunk * BC + quad * 4 + r) * TTS];
  }

  for (int t = 0; t < TTS; ++t) {
    const int par = t & 1, nxt = par ^ 1;
    const bool batch_start = (t & Km) == 0;
    const bool batch_last  = (t & Km) == Km;

    // ---- batch boundary: spin (all 64 lanes, uniform), acquire, load slot t
    if (batch_start) {
      if (layer > 0) {
        while (__hip_atomic_load(prog_in, __ATOMIC_RELAXED, __HIP_MEMORY_SCOPE_AGENT) < t + Kv)
          __builtin_amdgcn_s_sleep(1);
        (void)__hip_atomic_load(prog_in, __ATOMIC_ACQUIRE, __HIP_MEMORY_SCOPE_AGENT);
        const float* src = ring_in + (size_t)(t & RDm) * slot_sz + (size_t)lp * HH;
        #pragma unroll
        for (int kc = 0; kc < 4; ++kc) {
          const int s = kc * 32 + quad * 8;
          a_cur[kc][0] = (s < HH)     ? *(const f32x4*)(src + s)     : f32x4{};
          a_cur[kc][1] = (s + 4 < HH) ? *(const f32x4*)(src + s + 4) : f32x4{};
        }
      }
      if (layer < NL - 1 && t + Kv > RDv) {
        while (__hip_atomic_load(cons_out, __ATOMIC_RELAXED, __HIP_MEMORY_SCOPE_AGENT) < t + Kv - RDv)
          __builtin_amdgcn_s_sleep(1);
      }
    } else if (have_next) {
      #pragma unroll
      for (int kc = 0; kc < 4; ++kc) {
        a_cur[kc][0] = a_nxt[kc][0];
        a_cur[kc][1] = a_nxt[kc][1];
      }
    }
    have_next = false;

    // ---- prefetch inp/x for t+1 ----
    if (layer > 0) {
      if (!batch_last && t + 1 < TTS) {
        const float* src = ring_in + (size_t)((t + 1) & RDm) * slot_sz + (size_t)lp * HH;
        #pragma unroll
        for (int kc = 0; kc < 4; ++kc) {
          const int s = kc * 32 + quad * 8;
          a_nxt[kc][0] = (s < HH)     ? *(const f32x4*)(src + s)     : f32x4{};
          a_nxt[kc][1] = (s + 4 < HH) ? *(const f32x4*)(src + s + 4) : f32x4{};
        }
        have_next = true;
      }
    } else if (t + 1 < TTS) {
      #pragma unroll
      for (int r = 0; r < 4; ++r)
        px[r] = x[(size_t)(chunk * BC + quad * 4 + r) * TTS + (t + 1)];
    }

    // ---- MFMA: 7 independent acc chains; h from LDS, inp from regs ----
    f32x4 acc[NTL] = {};
    #pragma unroll
    for (int kc = 0; kc < 4; ++kc) {
      const float* rp = &hb[par][lp][kc * 32 + quad * 8];
      short8 A = build1(*(const f32x4*)rp, *(const f32x4*)(rp + 4));
      #pragma unroll
      for (int ntl = 0; ntl < NTL; ++ntl)
        acc[ntl] = __builtin_amdgcn_mfma_f32_16x16x32_bf16(A, Bf[kc][ntl], acc[ntl], 0, 0, 0);
    }
    if (layer > 0) {
      #pragma unroll
      for (int kc = 0; kc < 4; ++kc) {
        short8 A = build1(a_cur[kc][0], a_cur[kc][1]);
        #pragma unroll
        for (int ntl = 0; ntl < NTL; ++ntl)
          acc[ntl] = __builtin_amdgcn_mfma_f32_16x16x32_bf16(A, Bf[kc + 4][ntl], acc[ntl], 0, 0, 0);
      }
    }

    // ---- epilogue: bias(+x*w0), tanh, write hb[nxt] + ring + outputs ----
    float* rdst = (layer < NL - 1) ? ring_out + (size_t)(t & RDm) * slot_sz : nullptr;
    #pragma unroll
    for (int r = 0; r < 4; ++r) {
      const int row = quad * 4 + r;
      float s9 = 0.f;
      #pragma unroll
      for (int ntl = 0; ntl < NTL; ++ntl) {
        float v = acc[ntl][r] + br[ntl];
        if (layer == 0) v += xr[r] * w0r[ntl];
        float h = fast_tanh(v);
        const int col = ntl * 16 + lp;
        if (col < HH) {
          hb[nxt][row][col] = h;
          if (layer < NL - 1) rdst[(size_t)row * HH + col] = h;
          if (t == TTS - 1)
            out[(size_t)BBS * TTS +
                ((size_t)layer * BBS + chunk * BC + row) * HH + col] = h;
        }
        if (layer == NL - 1) s9 += h * wo[ntl];
      }
      if (layer == NL - 1) {   // reduce over 16 lp lanes (one 16-lane segment)
        s9 += __shfl_xor(s9, 1, 16);
        s9 += __shfl_xor(s9, 2, 16);
        s9 += __shfl_xor(s9, 4, 16);
        s9 += __shfl_xor(s9, 8, 16);
        if (lp == 0)
          out[(size_t)(chunk * BC + row) * TTS + t] = s9 + boutv;
      }
    }

    if (layer == 0 && t + 1 < TTS) {
      #pragma unroll
      for (int r = 0; r < 4; ++r) xr[r] = px[r];
    }

    // ---- flags (once per batch); single wave -> RELEASE covers all stores
    if (batch_last && tid == 0) {
      if (layer < NL - 1)
        __hip_atomic_store(prog_out, t + 1, __ATOMIC_RELEASE, __HIP_MEMORY_SCOPE_AGENT);
      if (layer > 0)
        __hip_atomic_store(cons_in, t + 1, __ATOMIC_RELAXED, __HIP_MEMORY_SCOPE_AGENT);
    }
  }
}

extern "C" void kernel_launch(void* const* d_in, const int* in_sizes, int n_in,
                              void* d_out, int out_size, void* d_ws, size_t ws_size,
                              hipStream_t stream) {
  const float* x    = (const float*)d_in[0];
  const float* h0   = (const float*)d_in[1];
  const float* Wih0 = (const float*)d_in[2];
  const float* Wih  = (const float*)d_in[3];
  const float* Whh  = (const float*)d_in[4];
  const float* bih  = (const float*)d_in[5];
  const float* bhh  = (const float*)d_in[6];
  const float* Wout = (const float*)d_in[7];
  const float* bout = (const float*)d_in[8];
  float* out = (float*)d_out;

  int*   wsi  = (int*)d_ws;
  float* ring = (float*)((char*)d_ws + 65536);

  // Pick deepest ring that fits ws: ring bytes = 9*32 * RD * 6400
  const size_t slot_bytes = (size_t)BC * HH * 4;   // 6400
  int RDv = 32;
  while (RDv > 2 && 65536 + (size_t)(NL - 1) * NB * RDv * slot_bytes > ws_size)
    RDv >>= 1;
  int Kv = RDv / 2;

  hipLaunchKernelGGL(init_ws_kernel, dim3(64), dim3(256), 0, stream, wsi);
  hipLaunchKernelGGL(rnn_pipe, dim3(NL * NB), dim3(NT), 0, stream,
                     x, h0, Wih0, Wih, Whh, bih, bhh, Wout, bout, out, ring, wsi,
                     Kv, RDv);
}